// Round 8
// baseline (287.621 us; speedup 1.0000x reference)
//
#include <hip/hip_runtime.h>
#include <math.h>

#define NN 10000
#define NE 100000
#define CC 6
#define LL 6
#define BB 16
#define FUNC_LO 100
#define FUNC_HI 9900
#define EPSF 1e-5f
#define NSLOT 64

struct Slot { double s1, s2; double pad[6]; };  // 64B-padded

struct Params {
  const float *x, *w1v, *b1, *w2v, *b2, *w3v, *b3, *gamma, *beta;
  const int *src, *dst, *w3r, *w3c;
  float *out;
  int *row_start, *counts, *fill, *slot;     // dst-CSR rows; slot[e] = position of e
  int *row2, *counts2, *fill2, *csr2;        // func node -> outgoing selected-edge rows (k)
  float4 *grec;   // per dst-slot:  {w1[0..3]} {w1[4],w1[5],src(bits),b3}
  float4 *srec;   // per src-slot:  {w3[0..3]} {w3[4],w3[5],slot(bits),b3}
  float *xT, *h, *z3a, *z3b;
  Slot *part, *baseS;
  int F, Ksel;
};

__device__ __forceinline__ float eluf(float x){ return x > 0.0f ? x : expm1f(x); }

__device__ void block_add_slot(double a, double q, Slot* sl){
  __shared__ double sb1[4], sb2[4];
  #pragma unroll
  for(int off=32;off;off>>=1){ a+=__shfl_down(a,off); q+=__shfl_down(q,off); }
  int wid = threadIdx.x>>6;
  if((threadIdx.x&63)==0){ sb1[wid]=a; sb2[wid]=q; }
  __syncthreads();
  if(threadIdx.x==0){
    double A=sb1[0]+sb1[1]+sb1[2]+sb1[3];
    double Q=sb2[0]+sb2[1]+sb2[2]+sb2[3];
    if(A!=0.0) atomicAdd(&sl->s1,A);
    if(Q!=0.0) atomicAdd(&sl->s2,Q);
  }
  __syncthreads();
}

__device__ void bn_params(const Slot* part, const Slot* baseS, float* m, float* inv){
  __shared__ double s_mv[2];
  if(threadIdx.x < NSLOT){
    double a = part[threadIdx.x].s1 + baseS[threadIdx.x].s1;
    double q = part[threadIdx.x].s2 + baseS[threadIdx.x].s2;
    #pragma unroll
    for(int off=32;off;off>>=1){ a+=__shfl_down(a,off); q+=__shfl_down(q,off); }
    if(threadIdx.x==0){
      const double cnt = (double)NE*(double)BB;
      double md = a/cnt, vd = q/cnt - md*md;
      s_mv[0]=md; s_mv[1]=1.0/sqrt(vd+(double)EPSF);
    }
  }
  __syncthreads();
  *m=(float)s_mv[0]; *inv=(float)s_mv[1];
  __syncthreads();
}

// P1: transpose x -> xT; dst histogram; src-selected histogram; base BN sums
// (non-func-src edges keep z3 = b3[e] every layer -> constant contribution).
__global__ __launch_bounds__(256) void kw_P1(Params p){
  int tid = blockIdx.x*256 + threadIdx.x, nt = gridDim.x*256;
  for(int i=tid;i<NN*BB;i+=nt){ int n=i>>4, b=i&15; p.xT[i]=p.x[b*NN+n]; }
  double a=0.0,q=0.0;
  for(int e=tid;e<NE;e+=nt){
    atomicAdd(&p.counts[p.dst[e]],1);
    int s=p.src[e];
    if(!(s>=FUNC_LO && s<FUNC_HI)){ double v=(double)p.b3[e]; a+=v; q+=v*v; }
  }
  for(int k=tid;k<p.Ksel;k+=nt){
    int s=p.w3r[k*CC]/CC;
    atomicAdd(&p.counts2[s-FUNC_LO],1);
  }
  block_add_slot(a*BB, q*BB, &p.baseS[blockIdx.x&(NSLOT-1)]);
}

// Two independent single-block scans: block 0 -> dst-CSR, block 1 -> src-CSR.
__global__ __launch_bounds__(256) void kw_scan(Params p){
  __shared__ int s_scan[256];
  const int*  cin  = (blockIdx.x==0)? p.counts : p.counts2;
  int*        rout = (blockIdx.x==0)? p.row_start : p.row2;
  const int   nel  = (blockIdx.x==0)? NN : p.F;
  const int   CH   = (nel+255)/256;
  int t=threadIdx.x, base=t*CH, s=0;
  for(int k=0;k<CH;k++){ int i=base+k; if(i<nel) s+=cin[i]; }
  s_scan[t]=s; __syncthreads();
  for(int off=1;off<256;off<<=1){
    int v=(t>=off)?s_scan[t-off]:0; __syncthreads();
    s_scan[t]+=v; __syncthreads();
  }
  int run=s_scan[t]-s;
  for(int k=0;k<CH;k++){ int i=base+k; if(i<nel){ rout[i]=run; run+=cin[i]; } }
  if(t==255) rout[nel]=s_scan[255];
}

// Fill: dst-CSR -> slot[e] + gather records; src-CSR -> csr2.
__global__ __launch_bounds__(256) void kw_fill(Params p){
  int tid = blockIdx.x*256 + threadIdx.x, nt = gridDim.x*256;
  for(int e=tid;e<NE;e+=nt){
    int n=p.dst[e];
    int pos=p.row_start[n]+atomicAdd(&p.fill[n],1);
    p.slot[e]=pos;
    const float* w=&p.w1v[e*CC];
    p.grec[pos*2  ]=make_float4(w[0],w[1],w[2],w[3]);
    p.grec[pos*2+1]=make_float4(w[4],w[5],__int_as_float(p.src[e]),p.b3[e]);
  }
  for(int k=tid;k<p.Ksel;k+=nt){
    int fi=p.w3r[k*CC]/CC - FUNC_LO;
    int pos=p.row2[fi]+atomicAdd(&p.fill2[fi],1);
    p.csr2[pos]=k;
  }
}

// AB_l (fused, slot-indexed, wave-per-node): lane = (b = lane&15, j = lane>>4);
// subgroup j handles slot pp0+j -> 256B contiguous reads per wave-iteration.
// z1 reduced across j via shfl_xor(16/32). l==0 additionally BUILDS srec from
// csr2/w3c/w3v/slot (removes the prep kernel); l>0 streams srec.
// BN_{l-1}+residual applied to h in place during the gather; out-dst slots in
// a separate coalesced tail loop. z3 ping-pongs (z3p -> z3c).
__global__ __launch_bounds__(256) void kw_AB(Params p, int l,
    const float* __restrict__ z3p, float* __restrict__ z3c){
  int gtid = blockIdx.x*256 + (int)threadIdx.x;
  int wave = gtid>>6, nw = (gridDim.x*256)>>6;
  int lane = threadIdx.x & 63;
  int b = lane & 15, j = lane >> 4;
  float m=0.f, inv=0.f, g=0.f, be=0.f;
  if(l>0){
    bn_params(p.part+(l-1)*NSLOT, p.baseS, &m, &inv);
    g=p.gamma[l-1]; be=p.beta[l-1];
  }
  double a=0.0, q=0.0;
  for(int fi=wave; fi<p.F; fi+=nw){
    int n=FUNC_LO+fi;
    float acc[CC];
    #pragma unroll
    for(int i=0;i<CC;i++) acc[i]=0.f;
    int beg=p.row_start[n], end=p.row_start[n+1];
    for(int pp0=beg; pp0<end; pp0+=4){
      int pp=pp0+j;
      if(pp<end){
        float4 ra=p.grec[pp*2], rb=p.grec[pp*2+1];
        int s=__float_as_int(rb.z);
        float hv;
        if(l==0){
          hv = p.xT[s*BB+b];
        } else {
          float zb=(s>=FUNC_LO&&s<FUNC_HI)? z3p[pp*BB+b] : rb.w;
          float hb=(l==1)? p.xT[s*BB+b] : p.h[pp*BB+b];
          hv = hb + (zb-m)*inv*g+be;
          p.h[pp*BB+b]=hv;
        }
        acc[0]+=hv*ra.x; acc[1]+=hv*ra.y; acc[2]+=hv*ra.z;
        acc[3]+=hv*ra.w; acc[4]+=hv*rb.x; acc[5]+=hv*rb.y;
      }
    }
    #pragma unroll
    for(int i=0;i<CC;i++){
      acc[i] += __shfl_xor(acc[i],16);
      acc[i] += __shfl_xor(acc[i],32);
      acc[i]  = eluf(acc[i] + p.b1[n*CC+i]);
    }
    const float* W2=&p.w2v[fi*36];
    float z2[CC];
    #pragma unroll
    for(int jj=0;jj<CC;jj++){
      float o=p.b2[n*CC+jj];
      #pragma unroll
      for(int i=0;i<CC;i++) o+=acc[i]*W2[i*CC+jj];
      z2[jj]=eluf(o);
    }
    int bg2=p.row2[fi], en2=p.row2[fi+1];
    if(l==0){
      for(int pp0=bg2; pp0<en2; pp0+=4){
        int pp=pp0+j;
        if(pp<en2){
          int k=p.csr2[pp];
          int e=p.w3c[k*CC];
          const float* w=&p.w3v[k*CC];
          float b3v=p.b3[e];
          int sl=p.slot[e];
          if(b==0){
            p.srec[pp*2  ]=make_float4(w[0],w[1],w[2],w[3]);
            p.srec[pp*2+1]=make_float4(w[4],w[5],__int_as_float(sl),b3v);
          }
          float o = b3v + z2[0]*w[0]+z2[1]*w[1]+z2[2]*w[2]
                        + z2[3]*w[3]+z2[4]*w[4]+z2[5]*w[5];
          z3c[sl*BB+b]=o;
          a+=o; q+=(double)o*o;
        }
      }
    } else {
      for(int pp0=bg2; pp0<en2; pp0+=4){
        int pp=pp0+j;
        if(pp<en2){
          float4 ra=p.srec[pp*2], rb=p.srec[pp*2+1];
          float o = rb.w + z2[0]*ra.x + z2[1]*ra.y + z2[2]*ra.z
                         + z2[3]*ra.w + z2[4]*rb.x + z2[5]*rb.y;
          int sl=__float_as_int(rb.z);
          z3c[sl*BB+b]=o;
          a+=o; q+=(double)o*o;
        }
      }
    }
  }
  // out-dst slots: BN+residual only (coalesced linear tail)
  if(l>0){
    int outBeg = p.row_start[FUNC_HI];
    int tot = (p.row_start[NN]-outBeg)*BB;
    int nt = gridDim.x*256;
    for(int u=gtid; u<tot; u+=nt){
      int pp=outBeg+(u>>4); int bb=u&15;
      float4 rb=p.grec[pp*2+1];
      int s=__float_as_int(rb.z);
      float zb=(s>=FUNC_LO&&s<FUNC_HI)? z3p[pp*BB+bb] : rb.w;
      float hb=(l==1)? p.xT[s*BB+bb] : p.h[pp*BB+bb];
      p.h[pp*BB+bb]=hb+(zb-m)*inv*g+be;
    }
  }
  block_add_slot(a,q,&p.part[l*NSLOT+(blockIdx.x&(NSLOT-1))]);
}

// out: apply BN_{L-1} inline to out-dst slots, sum per output node, /L.
__global__ __launch_bounds__(256) void kw_out(Params p, const float* __restrict__ z3p){
  int tid = blockIdx.x*256 + threadIdx.x, nt = gridDim.x*256;
  float m,inv;
  bn_params(p.part+(LL-1)*NSLOT, p.baseS, &m, &inv);
  float g=p.gamma[LL-1], be=p.beta[LL-1];
  for(int idx=tid;idx<BB*NN;idx+=nt){
    int b=idx/NN, n=idx-b*NN;
    float acc=0.f;
    if(n>=FUNC_HI){
      int beg=p.row_start[n], end=p.row_start[n+1];
      for(int pp=beg;pp<end;++pp){
        float4 rb=p.grec[pp*2+1];
        int s=__float_as_int(rb.z);
        float zb=(s>=FUNC_LO&&s<FUNC_HI)? z3p[pp*BB+b] : rb.w;
        acc += p.h[pp*BB+b] + (zb-m)*inv*g+be;
      }
      acc *= (1.0f/(float)LL);
    }
    p.out[idx]=acc;
  }
}

extern "C" void kernel_launch(void* const* d_in, const int* in_sizes, int n_in,
                              void* d_out, int out_size, void* d_ws, size_t ws_size,
                              hipStream_t stream){
  Params p;
  p.x    =(const float*)d_in[0];
  p.src  =(const int*)  d_in[1];
  p.dst  =(const int*)  d_in[2];
  p.w1v  =(const float*)d_in[6];
  p.b1   =(const float*)d_in[7];
  p.w2v  =(const float*)d_in[10];
  p.b2   =(const float*)d_in[11];
  p.w3r  =(const int*)  d_in[12];
  p.w3c  =(const int*)  d_in[13];
  p.w3v  =(const float*)d_in[14];
  p.b3   =(const float*)d_in[15];
  p.gamma=(const float*)d_in[16];
  p.beta =(const float*)d_in[17];
  p.out  =(float*)d_out;
  p.F    = in_sizes[8]/36;
  p.Ksel = in_sizes[12]/CC;

  char* ws=(char*)d_ws; size_t off=0;
  auto alloc=[&](size_t bytes)->char*{
    char* q=ws+off; off=(off+bytes+255)&~(size_t)255; return q;
  };
  p.row_start=(int*)   alloc((NN+1)*sizeof(int));
  p.row2     =(int*)   alloc((size_t)(p.F+1)*sizeof(int));
  p.slot     =(int*)   alloc(NE*sizeof(int));
  p.csr2     =(int*)   alloc(NE*sizeof(int));
  p.grec     =(float4*)alloc((size_t)NE*2*sizeof(float4));
  p.srec     =(float4*)alloc((size_t)NE*2*sizeof(float4));
  p.xT       =(float*) alloc((size_t)NN*BB*sizeof(float));
  p.h        =(float*) alloc((size_t)NE*BB*sizeof(float));
  p.z3a      =(float*) alloc((size_t)NE*BB*sizeof(float));
  p.z3b      =(float*) alloc((size_t)NE*BB*sizeof(float));
  // zero-initialized block (single memset): counts, fill, counts2, fill2, part, baseS
  p.counts   =(int*)  alloc(NN*sizeof(int));
  p.fill     =(int*)  alloc(NN*sizeof(int));
  p.counts2  =(int*)  alloc((size_t)p.F*sizeof(int));
  p.fill2    =(int*)  alloc((size_t)p.F*sizeof(int));
  p.part     =(Slot*) alloc((size_t)LL*NSLOT*sizeof(Slot));
  p.baseS    =(Slot*) alloc((size_t)NSLOT*sizeof(Slot));
  (void)ws_size; (void)n_in; (void)out_size;

  size_t zspan = (char*)(p.baseS+NSLOT) - (char*)p.counts;
  hipMemsetAsync(p.counts, 0, zspan, stream);

  float* bufs[2] = { p.z3a, p.z3b };

  kw_P1  <<<512,256,0,stream>>>(p);
  kw_scan<<<2,  256,0,stream>>>(p);
  kw_fill<<<512,256,0,stream>>>(p);
  for(int l=0;l<LL;l++){
    kw_AB<<<768,256,0,stream>>>(p, l, bufs[(l^1)&1], bufs[l&1]);
  }
  kw_out<<<(BB*NN+255)/256,256,0,stream>>>(p, bufs[(LL-1)&1]);
}

// Round 9
// 210.568 us; speedup vs baseline: 1.3659x; 1.3659x over previous
//
#include <hip/hip_runtime.h>
#include <math.h>

#define NN 10000
#define NE 100000
#define CC 6
#define LL 6
#define BB 16
#define FUNC_LO 100
#define FUNC_HI 9900
#define EPSF 1e-5f
#define NSLOT 64

struct Slot { double s1, s2; double pad[6]; };  // 64B-padded

struct Params {
  const float *x, *w1v, *b1, *w2v, *b2, *w3v, *b3, *gamma, *beta;
  const int *src, *dst, *w3r, *w3c;
  float *out;
  int *row_start, *counts, *fill, *slot;     // dst-CSR rows; slot[e] = position of e
  int *row2, *counts2, *fill2, *csr2;        // func node -> outgoing selected-edge rows (k)
  float4 *grec;   // per dst-slot:  {w1[0..3]} {w1[4],w1[5],src(bits),b3}
  float4 *srec;   // per src-slot:  {w3[0..3]} {w3[4],w3[5],slot(bits),b3}
  float *xT, *h, *z3a, *z3b;
  Slot *part, *baseS;
  int F, Ksel;
};

__device__ __forceinline__ float eluf(float x){ return x > 0.0f ? x : expm1f(x); }

__device__ void block_add_slot(double a, double q, Slot* sl){
  __shared__ double sb1[4], sb2[4];
  #pragma unroll
  for(int off=32;off;off>>=1){ a+=__shfl_down(a,off); q+=__shfl_down(q,off); }
  int wid = threadIdx.x>>6;
  if((threadIdx.x&63)==0){ sb1[wid]=a; sb2[wid]=q; }
  __syncthreads();
  if(threadIdx.x==0){
    double A=sb1[0]+sb1[1]+sb1[2]+sb1[3];
    double Q=sb2[0]+sb2[1]+sb2[2]+sb2[3];
    if(A!=0.0) atomicAdd(&sl->s1,A);
    if(Q!=0.0) atomicAdd(&sl->s2,Q);
  }
  __syncthreads();
}

__device__ void bn_params(const Slot* part, const Slot* baseS, float* m, float* inv){
  __shared__ double s_mv[2];
  if(threadIdx.x < NSLOT){
    double a = part[threadIdx.x].s1 + baseS[threadIdx.x].s1;
    double q = part[threadIdx.x].s2 + baseS[threadIdx.x].s2;
    #pragma unroll
    for(int off=32;off;off>>=1){ a+=__shfl_down(a,off); q+=__shfl_down(q,off); }
    if(threadIdx.x==0){
      const double cnt = (double)NE*(double)BB;
      double md = a/cnt, vd = q/cnt - md*md;
      s_mv[0]=md; s_mv[1]=1.0/sqrt(vd+(double)EPSF);
    }
  }
  __syncthreads();
  *m=(float)s_mv[0]; *inv=(float)s_mv[1];
  __syncthreads();
}

// P1: transpose x -> xT; dst histogram; src-selected histogram; base BN sums
// (non-func-src edges keep z3 = b3[e] every layer -> constant contribution).
__global__ __launch_bounds__(256) void kw_P1(Params p){
  int tid = blockIdx.x*256 + threadIdx.x, nt = gridDim.x*256;
  for(int i=tid;i<NN*BB;i+=nt){ int n=i>>4, b=i&15; p.xT[i]=p.x[b*NN+n]; }
  double a=0.0,q=0.0;
  for(int e=tid;e<NE;e+=nt){
    atomicAdd(&p.counts[p.dst[e]],1);
    int s=p.src[e];
    if(!(s>=FUNC_LO && s<FUNC_HI)){ double v=(double)p.b3[e]; a+=v; q+=v*v; }
  }
  for(int k=tid;k<p.Ksel;k+=nt){
    int s=p.w3r[k*CC]/CC;
    atomicAdd(&p.counts2[s-FUNC_LO],1);
  }
  block_add_slot(a*BB, q*BB, &p.baseS[blockIdx.x&(NSLOT-1)]);
}

// Two independent single-block scans: block 0 -> dst-CSR, block 1 -> src-CSR.
__global__ __launch_bounds__(256) void kw_scan(Params p){
  __shared__ int s_scan[256];
  const int*  cin  = (blockIdx.x==0)? p.counts : p.counts2;
  int*        rout = (blockIdx.x==0)? p.row_start : p.row2;
  const int   nel  = (blockIdx.x==0)? NN : p.F;
  const int   CH   = (nel+255)/256;
  int t=threadIdx.x, base=t*CH, s=0;
  for(int k=0;k<CH;k++){ int i=base+k; if(i<nel) s+=cin[i]; }
  s_scan[t]=s; __syncthreads();
  for(int off=1;off<256;off<<=1){
    int v=(t>=off)?s_scan[t-off]:0; __syncthreads();
    s_scan[t]+=v; __syncthreads();
  }
  int run=s_scan[t]-s;
  for(int k=0;k<CH;k++){ int i=base+k; if(i<nel){ rout[i]=run; run+=cin[i]; } }
  if(t==255) rout[nel]=s_scan[255];
}

// Fill: dst-CSR -> slot[e] + gather records; src-CSR -> csr2.
__global__ __launch_bounds__(256) void kw_fill(Params p){
  int tid = blockIdx.x*256 + threadIdx.x, nt = gridDim.x*256;
  for(int e=tid;e<NE;e+=nt){
    int n=p.dst[e];
    int pos=p.row_start[n]+atomicAdd(&p.fill[n],1);
    p.slot[e]=pos;
    const float* w=&p.w1v[e*CC];
    p.grec[pos*2  ]=make_float4(w[0],w[1],w[2],w[3]);
    p.grec[pos*2+1]=make_float4(w[4],w[5],__int_as_float(p.src[e]),p.b3[e]);
  }
  for(int k=tid;k<p.Ksel;k+=nt){
    int fi=p.w3r[k*CC]/CC - FUNC_LO;
    int pos=p.row2[fi]+atomicAdd(&p.fill2[fi],1);
    p.csr2[pos]=k;
  }
}

// AB_l (fused, slot-indexed, thread-per-(node,batch); 16-lane group per node).
// MODE 0: l==0  (h = xT, no BN; scatter builds srec in flight)
// MODE 1: l==1  (h base = xT, apply BN_0; write h)
// MODE 2: l>=2  (h base = h,  apply BN_{l-1}; write h)
// Gather loop manually unrolled x2 for memory-level parallelism.
template<int MODE>
__global__ __launch_bounds__(256) void kw_AB(Params p, int l,
    const float* __restrict__ z3p, float* __restrict__ z3c){
  int tid = blockIdx.x*256 + (int)threadIdx.x, nt = gridDim.x*256;
  float m=0.f, inv=0.f, g=0.f, be=0.f;
  if(MODE>0){
    bn_params(p.part+(l-1)*NSLOT, p.baseS, &m, &inv);
    g=p.gamma[l-1]; be=p.beta[l-1];
  }
  const int FB = p.F*BB;
  double a=0.0, q=0.0;
  for(int t=tid;t<FB;t+=nt){
    int fi=t>>4, b=t&15;
    int n=FUNC_LO+fi;
    float acc[CC];
    #pragma unroll
    for(int i=0;i<CC;i++) acc[i]=0.f;
    int beg=p.row_start[n], end=p.row_start[n+1];
    int pp=beg;
    for(; pp+2<=end; pp+=2){
      float4 ra0=p.grec[pp*2],   rb0=p.grec[pp*2+1];
      float4 ra1=p.grec[pp*2+2], rb1=p.grec[pp*2+3];
      int s0=__float_as_int(rb0.z), s1=__float_as_int(rb1.z);
      float hv0, hv1;
      if(MODE==0){
        hv0 = p.xT[s0*BB+b];
        hv1 = p.xT[s1*BB+b];
      } else {
        float zb0=(s0>=FUNC_LO&&s0<FUNC_HI)? z3p[pp*BB+b]     : rb0.w;
        float zb1=(s1>=FUNC_LO&&s1<FUNC_HI)? z3p[(pp+1)*BB+b] : rb1.w;
        float hb0=(MODE==1)? p.xT[s0*BB+b] : p.h[pp*BB+b];
        float hb1=(MODE==1)? p.xT[s1*BB+b] : p.h[(pp+1)*BB+b];
        hv0 = hb0 + (zb0-m)*inv*g+be;
        hv1 = hb1 + (zb1-m)*inv*g+be;
        p.h[pp*BB+b]=hv0; p.h[(pp+1)*BB+b]=hv1;
      }
      acc[0]+=hv0*ra0.x+hv1*ra1.x; acc[1]+=hv0*ra0.y+hv1*ra1.y;
      acc[2]+=hv0*ra0.z+hv1*ra1.z; acc[3]+=hv0*ra0.w+hv1*ra1.w;
      acc[4]+=hv0*rb0.x+hv1*rb1.x; acc[5]+=hv0*rb0.y+hv1*rb1.y;
    }
    if(pp<end){
      float4 ra0=p.grec[pp*2], rb0=p.grec[pp*2+1];
      int s0=__float_as_int(rb0.z);
      float hv0;
      if(MODE==0){
        hv0 = p.xT[s0*BB+b];
      } else {
        float zb0=(s0>=FUNC_LO&&s0<FUNC_HI)? z3p[pp*BB+b] : rb0.w;
        float hb0=(MODE==1)? p.xT[s0*BB+b] : p.h[pp*BB+b];
        hv0 = hb0 + (zb0-m)*inv*g+be;
        p.h[pp*BB+b]=hv0;
      }
      acc[0]+=hv0*ra0.x; acc[1]+=hv0*ra0.y; acc[2]+=hv0*ra0.z;
      acc[3]+=hv0*ra0.w; acc[4]+=hv0*rb0.x; acc[5]+=hv0*rb0.y;
    }
    #pragma unroll
    for(int i=0;i<CC;i++) acc[i]=eluf(acc[i]+p.b1[n*CC+i]);
    const float* W2=&p.w2v[fi*36];
    float z2[CC];
    #pragma unroll
    for(int jj=0;jj<CC;jj++){
      float o=p.b2[n*CC+jj];
      #pragma unroll
      for(int i=0;i<CC;i++) o+=acc[i]*W2[i*CC+jj];
      z2[jj]=eluf(o);
    }
    int bg2=p.row2[fi], en2=p.row2[fi+1];
    if(MODE==0){
      for(int sp=bg2;sp<en2;++sp){
        int k=p.csr2[sp];
        int e=p.w3c[k*CC];
        const float* w=&p.w3v[k*CC];
        float b3v=p.b3[e];
        int sl=p.slot[e];
        if(b==0){
          p.srec[sp*2  ]=make_float4(w[0],w[1],w[2],w[3]);
          p.srec[sp*2+1]=make_float4(w[4],w[5],__int_as_float(sl),b3v);
        }
        float o = b3v + z2[0]*w[0]+z2[1]*w[1]+z2[2]*w[2]
                      + z2[3]*w[3]+z2[4]*w[4]+z2[5]*w[5];
        z3c[sl*BB+b]=o;
        a+=o; q+=(double)o*o;
      }
    } else {
      for(int sp=bg2;sp<en2;++sp){
        float4 ra=p.srec[sp*2], rb=p.srec[sp*2+1];
        float o = rb.w + z2[0]*ra.x + z2[1]*ra.y + z2[2]*ra.z
                       + z2[3]*ra.w + z2[4]*rb.x + z2[5]*rb.y;
        int sl=__float_as_int(rb.z);
        z3c[sl*BB+b]=o;
        a+=o; q+=(double)o*o;
      }
    }
  }
  // out-dst slots: BN+residual only (coalesced linear tail)
  if(MODE>0){
    int outBeg = p.row_start[FUNC_HI];
    int tot = (p.row_start[NN]-outBeg)*BB;
    for(int u=tid; u<tot; u+=nt){
      int pp=outBeg+(u>>4); int bb=u&15;
      float4 rb=p.grec[pp*2+1];
      int s=__float_as_int(rb.z);
      float zb=(s>=FUNC_LO&&s<FUNC_HI)? z3p[pp*BB+bb] : rb.w;
      float hb=(MODE==1)? p.xT[s*BB+bb] : p.h[pp*BB+bb];
      p.h[pp*BB+bb]=hb+(zb-m)*inv*g+be;
    }
  }
  block_add_slot(a,q,&p.part[l*NSLOT+(blockIdx.x&(NSLOT-1))]);
}

// out: apply BN_{L-1} inline to out-dst slots, sum per output node, /L.
__global__ __launch_bounds__(256) void kw_out(Params p, const float* __restrict__ z3p){
  int tid = blockIdx.x*256 + threadIdx.x, nt = gridDim.x*256;
  float m,inv;
  bn_params(p.part+(LL-1)*NSLOT, p.baseS, &m, &inv);
  float g=p.gamma[LL-1], be=p.beta[LL-1];
  for(int idx=tid;idx<BB*NN;idx+=nt){
    int b=idx/NN, n=idx-b*NN;
    float acc=0.f;
    if(n>=FUNC_HI){
      int beg=p.row_start[n], end=p.row_start[n+1];
      for(int pp=beg;pp<end;++pp){
        float4 rb=p.grec[pp*2+1];
        int s=__float_as_int(rb.z);
        float zb=(s>=FUNC_LO&&s<FUNC_HI)? z3p[pp*BB+b] : rb.w;
        acc += p.h[pp*BB+b] + (zb-m)*inv*g+be;
      }
      acc *= (1.0f/(float)LL);
    }
    p.out[idx]=acc;
  }
}

extern "C" void kernel_launch(void* const* d_in, const int* in_sizes, int n_in,
                              void* d_out, int out_size, void* d_ws, size_t ws_size,
                              hipStream_t stream){
  Params p;
  p.x    =(const float*)d_in[0];
  p.src  =(const int*)  d_in[1];
  p.dst  =(const int*)  d_in[2];
  p.w1v  =(const float*)d_in[6];
  p.b1   =(const float*)d_in[7];
  p.w2v  =(const float*)d_in[10];
  p.b2   =(const float*)d_in[11];
  p.w3r  =(const int*)  d_in[12];
  p.w3c  =(const int*)  d_in[13];
  p.w3v  =(const float*)d_in[14];
  p.b3   =(const float*)d_in[15];
  p.gamma=(const float*)d_in[16];
  p.beta =(const float*)d_in[17];
  p.out  =(float*)d_out;
  p.F    = in_sizes[8]/36;
  p.Ksel = in_sizes[12]/CC;

  char* ws=(char*)d_ws; size_t off=0;
  auto alloc=[&](size_t bytes)->char*{
    char* q=ws+off; off=(off+bytes+255)&~(size_t)255; return q;
  };
  p.row_start=(int*)   alloc((NN+1)*sizeof(int));
  p.row2     =(int*)   alloc((size_t)(p.F+1)*sizeof(int));
  p.slot     =(int*)   alloc(NE*sizeof(int));
  p.csr2     =(int*)   alloc(NE*sizeof(int));
  p.grec     =(float4*)alloc((size_t)NE*2*sizeof(float4));
  p.srec     =(float4*)alloc((size_t)NE*2*sizeof(float4));
  p.xT       =(float*) alloc((size_t)NN*BB*sizeof(float));
  p.h        =(float*) alloc((size_t)NE*BB*sizeof(float));
  p.z3a      =(float*) alloc((size_t)NE*BB*sizeof(float));
  p.z3b      =(float*) alloc((size_t)NE*BB*sizeof(float));
  // zero-initialized block (single memset): counts, fill, counts2, fill2, part, baseS
  p.counts   =(int*)  alloc(NN*sizeof(int));
  p.fill     =(int*)  alloc(NN*sizeof(int));
  p.counts2  =(int*)  alloc((size_t)p.F*sizeof(int));
  p.fill2    =(int*)  alloc((size_t)p.F*sizeof(int));
  p.part     =(Slot*) alloc((size_t)LL*NSLOT*sizeof(Slot));
  p.baseS    =(Slot*) alloc((size_t)NSLOT*sizeof(Slot));
  (void)ws_size; (void)n_in; (void)out_size;

  size_t zspan = (char*)(p.baseS+NSLOT) - (char*)p.counts;
  hipMemsetAsync(p.counts, 0, zspan, stream);

  float* bufs[2] = { p.z3a, p.z3b };
  const int gridAB = (p.F*BB + 255)/256 + 32;   // node range + tail headroom

  kw_P1  <<<512,256,0,stream>>>(p);
  kw_scan<<<2,  256,0,stream>>>(p);
  kw_fill<<<512,256,0,stream>>>(p);
  kw_AB<0><<<gridAB,256,0,stream>>>(p, 0, bufs[1], bufs[0]);
  kw_AB<1><<<gridAB,256,0,stream>>>(p, 1, bufs[0], bufs[1]);
  for(int l=2;l<LL;l++){
    kw_AB<2><<<gridAB,256,0,stream>>>(p, l, bufs[(l^1)&1], bufs[l&1]);
  }
  kw_out<<<(BB*NN+255)/256,256,0,stream>>>(p, bufs[(LL-1)&1]);
}

// Round 10
// 172.294 us; speedup vs baseline: 1.6694x; 1.2221x over previous
//
#include <hip/hip_runtime.h>
#include <math.h>

#define NN 10000
#define NE 100000
#define CC 6
#define LL 6
#define BB 16
#define FUNC_LO 100
#define FUNC_HI 9900
#define EPSF 1e-5f
#define NSLOT 64

struct Slot { double s1, s2; double pad[6]; };  // 64B-padded

struct Params {
  const float *x, *w1v, *b1, *w2v, *b2, *w3v, *b3, *gamma, *beta;
  const int *src, *dst, *w3r, *w3c;
  float *out;
  int *row_start, *counts, *fill, *slot;     // dst-CSR rows; slot[e] = position of e
  int *row2, *counts2, *fill2, *csr2;        // func node -> outgoing selected-edge rows (k)
  float4 *grec;   // per dst-slot:  {w1[0..3]} {w1[4],w1[5],src(bits),b3}
  float4 *srec;   // per src-slot:  {w3[0..3]} {w3[4],w3[5],slot(bits),b3}
  float *xT, *h, *z3a, *z3b;
  Slot *part, *baseS;
  int F, Ksel;
};

__device__ __forceinline__ float eluf(float x){ return x > 0.0f ? x : expm1f(x); }

__device__ void block_add_slot(double a, double q, Slot* sl){
  __shared__ double sb1[4], sb2[4];
  #pragma unroll
  for(int off=32;off;off>>=1){ a+=__shfl_down(a,off); q+=__shfl_down(q,off); }
  int wid = threadIdx.x>>6;
  if((threadIdx.x&63)==0){ sb1[wid]=a; sb2[wid]=q; }
  __syncthreads();
  if(threadIdx.x==0){
    double A=sb1[0]+sb1[1]+sb1[2]+sb1[3];
    double Q=sb2[0]+sb2[1]+sb2[2]+sb2[3];
    if(A!=0.0) atomicAdd(&sl->s1,A);
    if(Q!=0.0) atomicAdd(&sl->s2,Q);
  }
  __syncthreads();
}

__device__ void bn_params(const Slot* part, const Slot* baseS, float* m, float* inv){
  __shared__ double s_mv[2];
  if(threadIdx.x < NSLOT){
    double a = part[threadIdx.x].s1 + baseS[threadIdx.x].s1;
    double q = part[threadIdx.x].s2 + baseS[threadIdx.x].s2;
    #pragma unroll
    for(int off=32;off;off>>=1){ a+=__shfl_down(a,off); q+=__shfl_down(q,off); }
    if(threadIdx.x==0){
      const double cnt = (double)NE*(double)BB;
      double md = a/cnt, vd = q/cnt - md*md;
      s_mv[0]=md; s_mv[1]=1.0/sqrt(vd+(double)EPSF);
    }
  }
  __syncthreads();
  *m=(float)s_mv[0]; *inv=(float)s_mv[1];
  __syncthreads();
}

// P1: transpose x -> xT; dst histogram; src-selected histogram; base BN sums
// (non-func-src edges keep z3 = b3[e] every layer -> constant contribution).
__global__ __launch_bounds__(256) void kw_P1(Params p){
  int tid = blockIdx.x*256 + threadIdx.x, nt = gridDim.x*256;
  for(int i=tid;i<NN*BB;i+=nt){ int n=i>>4, b=i&15; p.xT[i]=p.x[b*NN+n]; }
  double a=0.0,q=0.0;
  for(int e=tid;e<NE;e+=nt){
    atomicAdd(&p.counts[p.dst[e]],1);
    int s=p.src[e];
    if(!(s>=FUNC_LO && s<FUNC_HI)){ double v=(double)p.b3[e]; a+=v; q+=v*v; }
  }
  for(int k=tid;k<p.Ksel;k+=nt){
    int s=p.w3r[k*CC]/CC;
    atomicAdd(&p.counts2[s-FUNC_LO],1);
  }
  block_add_slot(a*BB, q*BB, &p.baseS[blockIdx.x&(NSLOT-1)]);
}

// Two independent single-block scans: block 0 -> dst-CSR, block 1 -> src-CSR.
__global__ __launch_bounds__(256) void kw_scan(Params p){
  __shared__ int s_scan[256];
  const int*  cin  = (blockIdx.x==0)? p.counts : p.counts2;
  int*        rout = (blockIdx.x==0)? p.row_start : p.row2;
  const int   nel  = (blockIdx.x==0)? NN : p.F;
  const int   CH   = (nel+255)/256;
  int t=threadIdx.x, base=t*CH, s=0;
  for(int k=0;k<CH;k++){ int i=base+k; if(i<nel) s+=cin[i]; }
  s_scan[t]=s; __syncthreads();
  for(int off=1;off<256;off<<=1){
    int v=(t>=off)?s_scan[t-off]:0; __syncthreads();
    s_scan[t]+=v; __syncthreads();
  }
  int run=s_scan[t]-s;
  for(int k=0;k<CH;k++){ int i=base+k; if(i<nel){ rout[i]=run; run+=cin[i]; } }
  if(t==255) rout[nel]=s_scan[255];
}

// Fill: dst-CSR -> slot[e] + gather records; non-func-src slots of BOTH z3
// buffers pre-filled with b3[e] (never overwritten later -> unconditional
// z3 reads in the layer kernels); src-CSR -> csr2.
__global__ __launch_bounds__(256) void kw_fill(Params p){
  int tid = blockIdx.x*256 + threadIdx.x, nt = gridDim.x*256;
  for(int e=tid;e<NE;e+=nt){
    int n=p.dst[e];
    int pos=p.row_start[n]+atomicAdd(&p.fill[n],1);
    p.slot[e]=pos;
    const float* w=&p.w1v[e*CC];
    int s=p.src[e];
    float b3v=p.b3[e];
    p.grec[pos*2  ]=make_float4(w[0],w[1],w[2],w[3]);
    p.grec[pos*2+1]=make_float4(w[4],w[5],__int_as_float(s),b3v);
    if(!(s>=FUNC_LO && s<FUNC_HI)){
      float4 v4=make_float4(b3v,b3v,b3v,b3v);
      float4* za=(float4*)&p.z3a[pos*BB];
      float4* zb=(float4*)&p.z3b[pos*BB];
      #pragma unroll
      for(int i=0;i<4;i++){ za[i]=v4; zb[i]=v4; }
    }
  }
  for(int k=tid;k<p.Ksel;k+=nt){
    int fi=p.w3r[k*CC]/CC - FUNC_LO;
    int pos=p.row2[fi]+atomicAdd(&p.fill2[fi],1);
    p.csr2[pos]=k;
  }
}

// AB_l (fused, slot-indexed). Thread layout: t = fi*32 + half*16 + b.
// Two 16-lane half-groups per node take alternating slots (stride 2, x2
// unrolled); z1 combined with one shfl_xor(16) per channel. Both halves then
// hold identical z2; the scatter range is split even/odd between halves.
// MODE 0: l==0  (h = xT, no BN; scatter builds srec in flight)
// MODE 1: l==1  (h base = xT, apply BN_0; write h)
// MODE 2: l>=2  (h base = h,  apply BN_{l-1}; write h)
// z3 reads are unconditional (non-func slots pre-filled with b3).
template<int MODE>
__global__ __launch_bounds__(256) void kw_AB(Params p, int l,
    const float* __restrict__ z3p, float* __restrict__ z3c){
  int tid = blockIdx.x*256 + (int)threadIdx.x, nt = gridDim.x*256;
  float c1=0.f, c2=0.f;
  if(MODE>0){
    float m, inv;
    bn_params(p.part+(l-1)*NSLOT, p.baseS, &m, &inv);
    float g=p.gamma[l-1], be=p.beta[l-1];
    c1 = inv*g; c2 = be - m*c1;
  }
  const int FB2 = p.F*32;
  double a=0.0, q=0.0;
  for(int t=tid;t<FB2;t+=nt){
    int fi = t>>5;
    int u  = t&31, b = u&15, half = u>>4;
    int n  = FUNC_LO+fi;
    float acc[CC];
    #pragma unroll
    for(int i=0;i<CC;i++) acc[i]=0.f;
    int beg=p.row_start[n], end=p.row_start[n+1];
    int pp = beg + half;
    for(; pp+2<end; pp+=4){
      float4 ra0=p.grec[pp*2],     rb0=p.grec[pp*2+1];
      float4 ra1=p.grec[(pp+2)*2], rb1=p.grec[(pp+2)*2+1];
      float hv0, hv1;
      if(MODE==0){
        int s0=__float_as_int(rb0.z), s1=__float_as_int(rb1.z);
        hv0 = p.xT[s0*BB+b];
        hv1 = p.xT[s1*BB+b];
      } else {
        float zb0=z3p[pp*BB+b], zb1=z3p[(pp+2)*BB+b];
        float hb0, hb1;
        if(MODE==1){
          int s0=__float_as_int(rb0.z), s1=__float_as_int(rb1.z);
          hb0=p.xT[s0*BB+b]; hb1=p.xT[s1*BB+b];
        } else {
          hb0=p.h[pp*BB+b]; hb1=p.h[(pp+2)*BB+b];
        }
        hv0 = hb0 + zb0*c1 + c2;
        hv1 = hb1 + zb1*c1 + c2;
        p.h[pp*BB+b]=hv0; p.h[(pp+2)*BB+b]=hv1;
      }
      acc[0]+=hv0*ra0.x+hv1*ra1.x; acc[1]+=hv0*ra0.y+hv1*ra1.y;
      acc[2]+=hv0*ra0.z+hv1*ra1.z; acc[3]+=hv0*ra0.w+hv1*ra1.w;
      acc[4]+=hv0*rb0.x+hv1*rb1.x; acc[5]+=hv0*rb0.y+hv1*rb1.y;
    }
    if(pp<end){
      float4 ra0=p.grec[pp*2], rb0=p.grec[pp*2+1];
      float hv0;
      if(MODE==0){
        int s0=__float_as_int(rb0.z);
        hv0 = p.xT[s0*BB+b];
      } else {
        float zb0=z3p[pp*BB+b];
        float hb0;
        if(MODE==1){ int s0=__float_as_int(rb0.z); hb0=p.xT[s0*BB+b]; }
        else       { hb0=p.h[pp*BB+b]; }
        hv0 = hb0 + zb0*c1 + c2;
        p.h[pp*BB+b]=hv0;
      }
      acc[0]+=hv0*ra0.x; acc[1]+=hv0*ra0.y; acc[2]+=hv0*ra0.z;
      acc[3]+=hv0*ra0.w; acc[4]+=hv0*rb0.x; acc[5]+=hv0*rb0.y;
    }
    #pragma unroll
    for(int i=0;i<CC;i++){
      acc[i] += __shfl_xor(acc[i],16);
      acc[i]  = eluf(acc[i] + p.b1[n*CC+i]);
    }
    const float* W2=&p.w2v[fi*36];
    float z2[CC];
    #pragma unroll
    for(int jj=0;jj<CC;jj++){
      float o=p.b2[n*CC+jj];
      #pragma unroll
      for(int i=0;i<CC;i++) o+=acc[i]*W2[i*CC+jj];
      z2[jj]=eluf(o);
    }
    int bg2=p.row2[fi], en2=p.row2[fi+1];
    if(MODE==0){
      for(int sp=bg2+half;sp<en2;sp+=2){
        int k=p.csr2[sp];
        int e=p.w3c[k*CC];
        const float* w=&p.w3v[k*CC];
        float b3v=p.b3[e];
        int sl=p.slot[e];
        if(b==0){
          p.srec[sp*2  ]=make_float4(w[0],w[1],w[2],w[3]);
          p.srec[sp*2+1]=make_float4(w[4],w[5],__int_as_float(sl),b3v);
        }
        float o = b3v + z2[0]*w[0]+z2[1]*w[1]+z2[2]*w[2]
                      + z2[3]*w[3]+z2[4]*w[4]+z2[5]*w[5];
        z3c[sl*BB+b]=o;
        a+=o; q+=(double)o*o;
      }
    } else {
      for(int sp=bg2+half;sp<en2;sp+=2){
        float4 ra=p.srec[sp*2], rb=p.srec[sp*2+1];
        float o = rb.w + z2[0]*ra.x + z2[1]*ra.y + z2[2]*ra.z
                       + z2[3]*ra.w + z2[4]*rb.x + z2[5]*rb.y;
        int sl=__float_as_int(rb.z);
        z3c[sl*BB+b]=o;
        a+=o; q+=(double)o*o;
      }
    }
  }
  // out-dst slots: BN+residual only (coalesced linear tail)
  if(MODE>0){
    int outBeg = p.row_start[FUNC_HI];
    int tot = (p.row_start[NN]-outBeg)*BB;
    for(int u=tid; u<tot; u+=nt){
      int pp=outBeg+(u>>4); int bb=u&15;
      float zb=z3p[pp*BB+bb];
      float hb;
      if(MODE==1){
        float4 rb=p.grec[pp*2+1];
        int s=__float_as_int(rb.z);
        hb=p.xT[s*BB+bb];
      } else {
        hb=p.h[pp*BB+bb];
      }
      p.h[pp*BB+bb]=hb+zb*c1+c2;
    }
  }
  block_add_slot(a,q,&p.part[l*NSLOT+(blockIdx.x&(NSLOT-1))]);
}

// out: apply BN_{L-1} inline to out-dst slots, sum per output node, /L.
__global__ __launch_bounds__(256) void kw_out(Params p, const float* __restrict__ z3p){
  int tid = blockIdx.x*256 + threadIdx.x, nt = gridDim.x*256;
  float m,inv;
  bn_params(p.part+(LL-1)*NSLOT, p.baseS, &m, &inv);
  float g=p.gamma[LL-1], be=p.beta[LL-1];
  float c1=inv*g, c2=be-m*c1;
  for(int idx=tid;idx<BB*NN;idx+=nt){
    int b=idx/NN, n=idx-b*NN;
    float acc=0.f;
    if(n>=FUNC_HI){
      int beg=p.row_start[n], end=p.row_start[n+1];
      for(int pp=beg;pp<end;++pp){
        acc += p.h[pp*BB+b] + z3p[pp*BB+b]*c1 + c2;
      }
      acc *= (1.0f/(float)LL);
    }
    p.out[idx]=acc;
  }
}

extern "C" void kernel_launch(void* const* d_in, const int* in_sizes, int n_in,
                              void* d_out, int out_size, void* d_ws, size_t ws_size,
                              hipStream_t stream){
  Params p;
  p.x    =(const float*)d_in[0];
  p.src  =(const int*)  d_in[1];
  p.dst  =(const int*)  d_in[2];
  p.w1v  =(const float*)d_in[6];
  p.b1   =(const float*)d_in[7];
  p.w2v  =(const float*)d_in[10];
  p.b2   =(const float*)d_in[11];
  p.w3r  =(const int*)  d_in[12];
  p.w3c  =(const int*)  d_in[13];
  p.w3v  =(const float*)d_in[14];
  p.b3   =(const float*)d_in[15];
  p.gamma=(const float*)d_in[16];
  p.beta =(const float*)d_in[17];
  p.out  =(float*)d_out;
  p.F    = in_sizes[8]/36;
  p.Ksel = in_sizes[12]/CC;

  char* ws=(char*)d_ws; size_t off=0;
  auto alloc=[&](size_t bytes)->char*{
    char* q=ws+off; off=(off+bytes+255)&~(size_t)255; return q;
  };
  p.row_start=(int*)   alloc((NN+1)*sizeof(int));
  p.row2     =(int*)   alloc((size_t)(p.F+1)*sizeof(int));
  p.slot     =(int*)   alloc(NE*sizeof(int));
  p.csr2     =(int*)   alloc(NE*sizeof(int));
  p.grec     =(float4*)alloc((size_t)NE*2*sizeof(float4));
  p.srec     =(float4*)alloc((size_t)NE*2*sizeof(float4));
  p.xT       =(float*) alloc((size_t)NN*BB*sizeof(float));
  p.h        =(float*) alloc((size_t)NE*BB*sizeof(float));
  p.z3a      =(float*) alloc((size_t)NE*BB*sizeof(float));
  p.z3b      =(float*) alloc((size_t)NE*BB*sizeof(float));
  // zero-initialized block (single memset): counts, fill, counts2, fill2, part, baseS
  p.counts   =(int*)  alloc(NN*sizeof(int));
  p.fill     =(int*)  alloc(NN*sizeof(int));
  p.counts2  =(int*)  alloc((size_t)p.F*sizeof(int));
  p.fill2    =(int*)  alloc((size_t)p.F*sizeof(int));
  p.part     =(Slot*) alloc((size_t)LL*NSLOT*sizeof(Slot));
  p.baseS    =(Slot*) alloc((size_t)NSLOT*sizeof(Slot));
  (void)ws_size; (void)n_in; (void)out_size;

  size_t zspan = (char*)(p.baseS+NSLOT) - (char*)p.counts;
  hipMemsetAsync(p.counts, 0, zspan, stream);

  float* bufs[2] = { p.z3a, p.z3b };
  const int gridAB = (p.F*32 + 255)/256;

  kw_P1  <<<512,256,0,stream>>>(p);
  kw_scan<<<2,  256,0,stream>>>(p);
  kw_fill<<<512,256,0,stream>>>(p);
  kw_AB<0><<<gridAB,256,0,stream>>>(p, 0, bufs[1], bufs[0]);
  kw_AB<1><<<gridAB,256,0,stream>>>(p, 1, bufs[0], bufs[1]);
  for(int l=2;l<LL;l++){
    kw_AB<2><<<gridAB,256,0,stream>>>(p, l, bufs[(l^1)&1], bufs[l&1]);
  }
  kw_out<<<(BB*NN+255)/256,256,0,stream>>>(p, bufs[(LL-1)&1]);
}